// Round 13
// baseline (14.774 us; speedup 1.0000x reference)
//
#include <hip/hip_runtime.h>

#define NEGV (-9e15f)
#define LOG2E 1.44269504088896340736f

// ---- DPP wave-64 reductions (ctrl must be an immediate -> template) ----
template<int CTRL>
__device__ __forceinline__ float dpp_add(float v) {
    const int t = __builtin_amdgcn_update_dpp(0, __float_as_int(v), CTRL, 0xf, 0xf, false);
    return v + __int_as_float(t);
}
template<int CTRL>
__device__ __forceinline__ float dpp_fmax(float v) {
    const int t = __builtin_amdgcn_update_dpp(__float_as_int(v), __float_as_int(v),
                                              CTRL, 0xf, 0xf, false);
    return fmaxf(v, __int_as_float(t));
}
__device__ __forceinline__ float rdlane(float v, int l) {
    return __int_as_float(__builtin_amdgcn_readlane(__float_as_int(v), l));
}
__device__ __forceinline__ float wsum(float v) {
    v = dpp_add<0x111>(v);
    v = dpp_add<0x112>(v);
    v = dpp_add<0x114>(v);
    v = dpp_add<0x118>(v);
    v = dpp_add<0x142>(v);  // row_bcast15
    v = dpp_add<0x143>(v);  // row_bcast31 -> lane63 = total
    return rdlane(v, 63);
}
__device__ __forceinline__ float wmax(float v) {
    v = dpp_fmax<0x111>(v);
    v = dpp_fmax<0x112>(v);
    v = dpp_fmax<0x114>(v);
    v = dpp_fmax<0x118>(v);
    v = dpp_fmax<0x142>(v);
    v = dpp_fmax<0x143>(v);
    return rdlane(v, 63);
}
__device__ __forceinline__ float rowscan16(float v) {
    v = dpp_add<0x111>(v);
    v = dpp_add<0x112>(v);
    v = dpp_add<0x114>(v);
    v = dpp_add<0x118>(v);
    return v;
}
__device__ __forceinline__ void ld8f(const float* p, float* o) {
    const float4 v0 = ((const float4*)p)[0];
    const float4 v1 = ((const float4*)p)[1];
    o[0] = v0.x; o[1] = v0.y; o[2] = v0.z; o[3] = v0.w;
    o[4] = v1.x; o[5] = v1.y; o[6] = v1.z; o[7] = v1.w;
}

__global__ __launch_bounds__(64) void sentinel_kernel(float* __restrict__ out) {
    out[blockIdx.x * 64 + threadIdx.x] = 111222.0f;
}

// R12 (best: 14.41us) + ONE change: exp2-direct d-softmax.
// weight_f = dv>0 ? 2^min(dv,120) : 0  -- softmax ratios identical to ref
// (common positive factor cancels); all-masked tile fixed up via ds==0 ->
// uniform 1/8 (matches ref exp(NEG-NEG)=1 path). Removes the per-(t,row)
// serial 7-fmax dm chain + 64 subtracts and the d0/d1[8] arrays (-16 VGPR).
__global__ __launch_bounds__(128, 4) void gat_fused_f32(
    const float* __restrict__ input, const int* __restrict__ adj,
    const float* __restrict__ ext, const float* __restrict__ side,
    const float* __restrict__ W, const float* __restrict__ a,
    const float* __restrict__ WS, const float* __restrict__ aS,
    const float* __restrict__ WQ, const float* __restrict__ WK,
    const float* __restrict__ WV, float* __restrict__ out)
{
    const int N = 512, F = 64;
    const int lane = threadIdx.x & 63;
    const int w = threadIdx.x >> 6;
    const int b = blockIdx.x >> 8;
    const int i0 = (blockIdx.x & 255) * 2;

    __shared__ float mrg[16];

    const int jbase = 256 * w;
    const int arow0 = i0 * N + jbase;

    // ---- probe + int32 mask loads issued together (independent) ----
    const int probe = adj[2 * lane + 1];
    const int* adji0 = adj + arow0;
    const int* adji1 = adji0 + N;
    int m0i[4], m1i[4];
#pragma unroll
    for (int t = 0; t < 4; t++) {
        const int jj = lane + 64 * t;
        m0i[t] = adji0[jj];
        m1i[t] = adji1[jj];
    }

    // ---- issue this wave's ext loads NOW; consumed in pass 2 from regs ----
    const float* ebase = ext + (size_t)(b * N + jbase) * 8;
    float4 stA[4], stB[4];
#pragma unroll
    for (int u = 0; u < 4; u++) {
        const float* p = ebase + (size_t)(u * 64 + lane) * 8;
        stA[u] = ((const float4*)p)[0];
        stB[u] = ((const float4*)p)[1];
    }

    // dtype select: cold path re-loads masks as int64 {0,1} pairs
    const bool adj64 = (__any(probe != 0) == 0);
    if (adj64) {
        const long long* adjl0 = (const long long*)adj + arow0;
        const long long* adjl1 = adjl0 + N;
#pragma unroll
        for (int t = 0; t < 4; t++) {
            const int jj = lane + 64 * t;
            m0i[t] = (adjl0[jj] != 0);
            m1i[t] = (adjl1[jj] != 0);
        }
    }

    // ---- weight contractions (log2e folded; exact for lrelu/masks) ----
    const float wf  = W[lane];
    const float wvf = WV[lane];
    const float c1  = wsum(wf * a[lane]) * LOG2E;
    const float c2  = wsum(wf * a[F + lane]) * LOG2E;
    const float wsf = WS[lane];
    const float cS1 = wsum(wsf * aS[lane]) * LOG2E;
    const float cS2 = wsum(wsf * aS[F + lane]) * LOG2E;

    // segmented QK contraction: group g computes q_{g>>1}.k_{g&1}
    const int g = lane >> 4, l16 = lane & 15;
    const float QS = 0.25f * LOG2E;
    float prod = WQ[(g >> 1) * 16 + l16] * WK[(g & 1) * 16 + l16];
    prod = rowscan16(prod);
    const float a00 = rdlane(prod, 15) * QS;
    const float a01 = rdlane(prod, 31) * QS;
    const float a10 = rdlane(prod, 47) * QS;
    const float a11 = rdlane(prod, 63) * QS;

    const int row0 = b * N + i0;
    const float x0 = input[row0], x1 = input[row0 + 1];
    const float y0 = side[row0],  y1 = side[row0 + 1];
    float ei0[8], ei1[8];
    ld8f(ext + (size_t)row0 * 8, ei0);
    ld8f(ext + (size_t)(row0 + 1) * 8, ei1);

    const float s10 = c1 * x0,  s11 = c1 * x1;
    const float t10 = cS1 * y0, t11 = cS1 * y1;

    // sum_f ext_i[f]/8 for the all-masked d-softmax fixup (uniform case)
    float se0 = 0.f, se1 = 0.f;
#pragma unroll
    for (int f = 0; f < 8; f++) { se0 += ei0[f]; se1 += ei1[f]; }
    se0 *= 0.125f; se1 *= 0.125f;

    const float* xp = input + b * N + jbase;
    const float* yp = side + b * N + jbase;

    // ---- pass 1: this wave's 256 logits for both rows ----
    float xj[4], L0[4], L1[4];
#pragma unroll
    for (int t = 0; t < 4; t++) {
        const int jj = lane + 64 * t;
        const float xv = xp[jj];
        const float yv = yp[jj];
        xj[t] = xv;
        const float z  = c2 * xv;
        const float zs = cS2 * yv;
        float u0 = s10 + z;  u0 = fmaxf(u0, 0.2f * u0);
        float v0 = t10 + zs; v0 = fmaxf(v0, 0.2f * v0);
        float u1 = s11 + z;  u1 = fmaxf(u1, 0.2f * u1);
        float v1 = t11 + zs; v1 = fmaxf(v1, 0.2f * v1);
        const float g0 = u0 + v0;
        const float g1 = u1 + v1;
        L0[t] = (m0i[t] != 0 && g0 > 0.f) ? g0 : NEGV;
        L1[t] = (m1i[t] != 0 && g1 > 0.f) ? g1 : NEGV;
    }
    float M0 = fmaxf(fmaxf(L0[0], L0[1]), fmaxf(L0[2], L0[3]));
    float M1 = fmaxf(fmaxf(L1[0], L1[1]), fmaxf(L1[2], L1[3]));
    M0 = wmax(M0); M1 = wmax(M1);

    float s0 = 0.f, s1 = 0.f;
#pragma unroll
    for (int t = 0; t < 4; t++) {
        L0[t] = __builtin_amdgcn_exp2f(L0[t] - M0); s0 += L0[t];  // L := E
        L1[t] = __builtin_amdgcn_exp2f(L1[t] - M1); s1 += L1[t];
    }

    // ---- pass 2: unnormalized A_w, R_w; exp2-direct d-softmax ----
    float A0 = 0.f, A1 = 0.f, R0 = 0.f, R1 = 0.f;
#pragma unroll
    for (int t = 0; t < 4; t++) {
        float ej[8];
        ej[0] = stA[t].x; ej[1] = stA[t].y; ej[2] = stA[t].z; ej[3] = stA[t].w;
        ej[4] = stB[t].x; ej[5] = stB[t].y; ej[6] = stB[t].z; ej[7] = stB[t].w;

        const float qj0 = xj[t] * a10, qj1 = xj[t] * a11;
        const float qk00 = x0 * a00 + qj0, qk01 = x0 * a01 + qj1;
        const float qk10 = x1 * a00 + qj0, qk11 = x1 * a01 + qj1;

        float ds0 = 0.f, ds1 = 0.f, dot0 = 0.f, dot1 = 0.f;
#pragma unroll
        for (int f = 0; f < 8; f++) {
            const float dv0 = ei0[f] * qk00 + ej[f] * qk01;
            const float dv1 = ei1[f] * qk10 + ej[f] * qk11;
            const float e0 = (dv0 > 0.f) ? __builtin_amdgcn_exp2f(fminf(dv0, 120.f)) : 0.f;
            const float e1 = (dv1 > 0.f) ? __builtin_amdgcn_exp2f(fminf(dv1, 120.f)) : 0.f;
            ds0 += e0; dot0 += e0 * ei0[f];
            ds1 += e1; dot1 += e1 * ei1[f];
        }
        // all-masked -> reference softmax is uniform 1/8
        const bool z0 = (ds0 == 0.f), z1 = (ds1 == 0.f);
        dot0 = z0 ? se0 : dot0;  ds0 = z0 ? 1.f : ds0;
        dot1 = z1 ? se1 : dot1;  ds1 = z1 ? 1.f : ds1;

        A0 += L0[t] * xj[t];
        A1 += L1[t] * xj[t];
        R0 += L0[t] * __builtin_amdgcn_rcpf(ds0) * dot0;
        R1 += L1[t] * __builtin_amdgcn_rcpf(ds1) * dot1;
    }
    s0 = wsum(s0); s1 = wsum(s1);
    A0 = wsum(A0); A1 = wsum(A1);
    R0 = wsum(R0); R1 = wsum(R1);

    // ---- cross-wave online-softmax merge (exact): one barrier ----
    if (lane == 0) {
        float* m = mrg + w * 8;
        m[0] = M0; m[1] = M1; m[2] = s0; m[3] = s1;
        m[4] = A0; m[5] = A1; m[6] = R0; m[7] = R1;
    }
    __syncthreads();

    const float Ma0 = fmaxf(mrg[0], mrg[8]);
    const float Ma1 = fmaxf(mrg[1], mrg[9]);
    const float p00 = __builtin_amdgcn_exp2f(mrg[0] - Ma0);  // NEGV-NEGV=0 -> 1
    const float p01 = __builtin_amdgcn_exp2f(mrg[8] - Ma0);
    const float p10 = __builtin_amdgcn_exp2f(mrg[1] - Ma1);
    const float p11 = __builtin_amdgcn_exp2f(mrg[9] - Ma1);
    const float inv0 = __builtin_amdgcn_rcpf(p00 * mrg[2] + p01 * mrg[10]);
    const float inv1 = __builtin_amdgcn_rcpf(p10 * mrg[3] + p11 * mrg[11]);

    const int o = row0 * F + lane;
    if (w == 0) {
        float o00 = (p00 * mrg[4] + p01 * mrg[12]) * inv0 * wf;
        float o01 = (p10 * mrg[5] + p11 * mrg[13]) * inv1 * wf;
        o00 = (o00 > 0.f) ? o00 : (__builtin_amdgcn_exp2f(o00 * LOG2E) - 1.f);
        o01 = (o01 > 0.f) ? o01 : (__builtin_amdgcn_exp2f(o01 * LOG2E) - 1.f);
        out[o] = o00;
        out[o + F] = o01;
    } else {
        float o10 = (p00 * mrg[6] + p01 * mrg[14]) * inv0 * wvf;
        float o11 = (p10 * mrg[7] + p11 * mrg[15]) * inv1 * wvf;
        o10 = (o10 > 0.f) ? o10 : (__builtin_amdgcn_exp2f(o10 * LOG2E) - 1.f);
        o11 = (o11 > 0.f) ? o11 : (__builtin_amdgcn_exp2f(o11 * LOG2E) - 1.f);
        out[262144 + o] = o10;      // 8*N*F
        out[262144 + o + F] = o11;
    }
}

extern "C" void kernel_launch(void* const* d_in, const int* in_sizes, int n_in,
                              void* d_out, int out_size, void* d_ws, size_t ws_size,
                              hipStream_t stream) {
    static const int exp_sizes[11] = {4096, 262144, 32768, 4096, 64, 128, 64, 128, 32, 32, 64};
    bool ok = (n_in == 11) && (out_size == 524288);
    if (ok) {
        for (int k = 0; k < 11; k++) if (in_sizes[k] != exp_sizes[k]) ok = false;
    }
    if (!ok) {
        sentinel_kernel<<<4096, 64, 0, stream>>>((float*)d_out);
        return;
    }

    gat_fused_f32<<<2048, 128, 0, stream>>>(
        (const float*)d_in[0], (const int*)d_in[1],
        (const float*)d_in[2], (const float*)d_in[3],
        (const float*)d_in[4], (const float*)d_in[5],
        (const float*)d_in[6], (const float*)d_in[7],
        (const float*)d_in[8], (const float*)d_in[9],
        (const float*)d_in[10],
        (float*)d_out);
}

// Round 14
// 12.977 us; speedup vs baseline: 1.1385x; 1.1385x over previous
//
#include <hip/hip_runtime.h>

#define NEGV (-9e15f)
#define LOG2E 1.44269504088896340736f

typedef float v2f __attribute__((ext_vector_type(2)));

// ---- DPP wave-64 reductions (ctrl must be an immediate -> template) ----
template<int CTRL>
__device__ __forceinline__ float dpp_add(float v) {
    const int t = __builtin_amdgcn_update_dpp(0, __float_as_int(v), CTRL, 0xf, 0xf, false);
    return v + __int_as_float(t);
}
template<int CTRL>
__device__ __forceinline__ float dpp_fmax(float v) {
    const int t = __builtin_amdgcn_update_dpp(__float_as_int(v), __float_as_int(v),
                                              CTRL, 0xf, 0xf, false);
    return fmaxf(v, __int_as_float(t));
}
__device__ __forceinline__ float rdlane(float v, int l) {
    return __int_as_float(__builtin_amdgcn_readlane(__float_as_int(v), l));
}
__device__ __forceinline__ float wsum(float v) {
    v = dpp_add<0x111>(v);
    v = dpp_add<0x112>(v);
    v = dpp_add<0x114>(v);
    v = dpp_add<0x118>(v);
    v = dpp_add<0x142>(v);  // row_bcast15
    v = dpp_add<0x143>(v);  // row_bcast31 -> lane63 = total
    return rdlane(v, 63);
}
__device__ __forceinline__ float wmax(float v) {
    v = dpp_fmax<0x111>(v);
    v = dpp_fmax<0x112>(v);
    v = dpp_fmax<0x114>(v);
    v = dpp_fmax<0x118>(v);
    v = dpp_fmax<0x142>(v);
    v = dpp_fmax<0x143>(v);
    return rdlane(v, 63);
}
__device__ __forceinline__ float rowscan16(float v) {
    v = dpp_add<0x111>(v);
    v = dpp_add<0x112>(v);
    v = dpp_add<0x114>(v);
    v = dpp_add<0x118>(v);
    return v;
}
__device__ __forceinline__ void ld8f(const float* p, float* o) {
    const float4 v0 = ((const float4*)p)[0];
    const float4 v1 = ((const float4*)p)[1];
    o[0] = v0.x; o[1] = v0.y; o[2] = v0.z; o[3] = v0.w;
    o[4] = v1.x; o[5] = v1.y; o[6] = v1.z; o[7] = v1.w;
}

__global__ __launch_bounds__(64) void sentinel_kernel(float* __restrict__ out) {
    out[blockIdx.x * 64 + threadIdx.x] = 111222.0f;
}

// R12 (best: 14.41us) + ONE change: pass-2 row-pair math in 2-wide vectors
// (ext_vector_type(2)) so the backend can select v_pk_fma_f32/v_pk_max_f32/
// v_pk_add_f32 (CDNA packed FP32: 2x work per issue). exp stays scalar.
// Softmax semantics byte-identical to R12 (dm chain kept; R13's exp2-direct
// variant regressed and is discarded).
__global__ __launch_bounds__(128, 4) void gat_fused_f32(
    const float* __restrict__ input, const int* __restrict__ adj,
    const float* __restrict__ ext, const float* __restrict__ side,
    const float* __restrict__ W, const float* __restrict__ a,
    const float* __restrict__ WS, const float* __restrict__ aS,
    const float* __restrict__ WQ, const float* __restrict__ WK,
    const float* __restrict__ WV, float* __restrict__ out)
{
    const int N = 512, F = 64;
    const int lane = threadIdx.x & 63;
    const int w = threadIdx.x >> 6;
    const int b = blockIdx.x >> 8;
    const int i0 = (blockIdx.x & 255) * 2;

    __shared__ float mrg[16];

    const int jbase = 256 * w;
    const int arow0 = i0 * N + jbase;

    // ---- probe + int32 mask loads issued together (independent) ----
    const int probe = adj[2 * lane + 1];
    const int* adji0 = adj + arow0;
    const int* adji1 = adji0 + N;
    int m0i[4], m1i[4];
#pragma unroll
    for (int t = 0; t < 4; t++) {
        const int jj = lane + 64 * t;
        m0i[t] = adji0[jj];
        m1i[t] = adji1[jj];
    }

    // ---- issue this wave's ext loads NOW; consumed in pass 2 from regs ----
    const float* ebase = ext + (size_t)(b * N + jbase) * 8;
    float4 stA[4], stB[4];
#pragma unroll
    for (int u = 0; u < 4; u++) {
        const float* p = ebase + (size_t)(u * 64 + lane) * 8;
        stA[u] = ((const float4*)p)[0];
        stB[u] = ((const float4*)p)[1];
    }

    // dtype select: cold path re-loads masks as int64 {0,1} pairs
    const bool adj64 = (__any(probe != 0) == 0);
    if (adj64) {
        const long long* adjl0 = (const long long*)adj + arow0;
        const long long* adjl1 = adjl0 + N;
#pragma unroll
        for (int t = 0; t < 4; t++) {
            const int jj = lane + 64 * t;
            m0i[t] = (adjl0[jj] != 0);
            m1i[t] = (adjl1[jj] != 0);
        }
    }

    // ---- weight contractions (log2e folded; exact for lrelu/masks) ----
    const float wf  = W[lane];
    const float wvf = WV[lane];
    const float c1  = wsum(wf * a[lane]) * LOG2E;
    const float c2  = wsum(wf * a[F + lane]) * LOG2E;
    const float wsf = WS[lane];
    const float cS1 = wsum(wsf * aS[lane]) * LOG2E;
    const float cS2 = wsum(wsf * aS[F + lane]) * LOG2E;

    // segmented QK contraction: group g computes q_{g>>1}.k_{g&1}
    const int g = lane >> 4, l16 = lane & 15;
    const float QS = 0.25f * LOG2E;
    float prod = WQ[(g >> 1) * 16 + l16] * WK[(g & 1) * 16 + l16];
    prod = rowscan16(prod);
    const float a00 = rdlane(prod, 15) * QS;
    const float a01 = rdlane(prod, 31) * QS;
    const float a10 = rdlane(prod, 47) * QS;
    const float a11 = rdlane(prod, 63) * QS;

    const int row0 = b * N + i0;
    const float x0 = input[row0], x1 = input[row0 + 1];
    const float y0 = side[row0],  y1 = side[row0 + 1];
    float ei0[8], ei1[8];
    ld8f(ext + (size_t)row0 * 8, ei0);
    ld8f(ext + (size_t)(row0 + 1) * 8, ei1);

    // row-paired ext_i for packed pass-2 math
    v2f eiv[8];
#pragma unroll
    for (int f = 0; f < 8; f++) eiv[f] = (v2f){ei0[f], ei1[f]};

    const float s10 = c1 * x0,  s11 = c1 * x1;
    const float t10 = cS1 * y0, t11 = cS1 * y1;

    const float* xp = input + b * N + jbase;
    const float* yp = side + b * N + jbase;

    // ---- pass 1: this wave's 256 logits for both rows ----
    float xj[4], L0[4], L1[4];
#pragma unroll
    for (int t = 0; t < 4; t++) {
        const int jj = lane + 64 * t;
        const float xv = xp[jj];
        const float yv = yp[jj];
        xj[t] = xv;
        const float z  = c2 * xv;
        const float zs = cS2 * yv;
        float u0 = s10 + z;  u0 = fmaxf(u0, 0.2f * u0);
        float v0 = t10 + zs; v0 = fmaxf(v0, 0.2f * v0);
        float u1 = s11 + z;  u1 = fmaxf(u1, 0.2f * u1);
        float v1 = t11 + zs; v1 = fmaxf(v1, 0.2f * v1);
        const float g0 = u0 + v0;
        const float g1 = u1 + v1;
        L0[t] = (m0i[t] != 0 && g0 > 0.f) ? g0 : NEGV;
        L1[t] = (m1i[t] != 0 && g1 > 0.f) ? g1 : NEGV;
    }
    float M0 = fmaxf(fmaxf(L0[0], L0[1]), fmaxf(L0[2], L0[3]));
    float M1 = fmaxf(fmaxf(L1[0], L1[1]), fmaxf(L1[2], L1[3]));
    M0 = wmax(M0); M1 = wmax(M1);

    float s0 = 0.f, s1 = 0.f;
#pragma unroll
    for (int t = 0; t < 4; t++) {
        L0[t] = __builtin_amdgcn_exp2f(L0[t] - M0); s0 += L0[t];  // L := E
        L1[t] = __builtin_amdgcn_exp2f(L1[t] - M1); s1 += L1[t];
    }

    // ---- pass 2: packed row-pair d-softmax (semantics = R12) ----
    float A0 = 0.f, A1 = 0.f;
    v2f Rv = (v2f){0.f, 0.f};
#pragma unroll
    for (int t = 0; t < 4; t++) {
        float ej[8];
        ej[0] = stA[t].x; ej[1] = stA[t].y; ej[2] = stA[t].z; ej[3] = stA[t].w;
        ej[4] = stB[t].x; ej[5] = stB[t].y; ej[6] = stB[t].z; ej[7] = stB[t].w;

        const float qj0 = xj[t] * a10, qj1 = xj[t] * a11;
        const v2f qk0v = (v2f){x0 * a00 + qj0, x1 * a00 + qj0};
        const v2f qk1v = (v2f){x0 * a01 + qj1, x1 * a01 + qj1};

        v2f d[8];
        v2f dm = (v2f){NEGV, NEGV};
#pragma unroll
        for (int f = 0; f < 8; f++) {
            v2f dv = eiv[f] * qk0v + (v2f){ej[f], ej[f]} * qk1v;  // pk_fma
            dv.x = (dv.x > 0.f) ? dv.x : NEGV;
            dv.y = (dv.y > 0.f) ? dv.y : NEGV;
            d[f] = dv;
            dm = __builtin_elementwise_max(dm, dv);               // pk_max
        }
        v2f ds = (v2f){0.f, 0.f}, dot = (v2f){0.f, 0.f};
#pragma unroll
        for (int f = 0; f < 8; f++) {
            const v2f sub = d[f] - dm;                            // pk_add
            const v2f e = (v2f){__builtin_amdgcn_exp2f(sub.x),
                                __builtin_amdgcn_exp2f(sub.y)};
            ds  += e;                                             // pk_add
            dot += e * eiv[f];                                    // pk_fma
        }
        A0 += L0[t] * xj[t];
        A1 += L1[t] * xj[t];
        const v2f Lv = (v2f){L0[t], L1[t]};
        const v2f rcp = (v2f){__builtin_amdgcn_rcpf(ds.x),
                              __builtin_amdgcn_rcpf(ds.y)};
        Rv += Lv * rcp * dot;                                     // pk ops
    }
    float R0 = Rv.x, R1 = Rv.y;
    s0 = wsum(s0); s1 = wsum(s1);
    A0 = wsum(A0); A1 = wsum(A1);
    R0 = wsum(R0); R1 = wsum(R1);

    // ---- cross-wave online-softmax merge (exact): one barrier ----
    if (lane == 0) {
        float* m = mrg + w * 8;
        m[0] = M0; m[1] = M1; m[2] = s0; m[3] = s1;
        m[4] = A0; m[5] = A1; m[6] = R0; m[7] = R1;
    }
    __syncthreads();

    const float Ma0 = fmaxf(mrg[0], mrg[8]);
    const float Ma1 = fmaxf(mrg[1], mrg[9]);
    const float p00 = __builtin_amdgcn_exp2f(mrg[0] - Ma0);  // NEGV-NEGV=0 -> 1
    const float p01 = __builtin_amdgcn_exp2f(mrg[8] - Ma0);
    const float p10 = __builtin_amdgcn_exp2f(mrg[1] - Ma1);
    const float p11 = __builtin_amdgcn_exp2f(mrg[9] - Ma1);
    const float inv0 = __builtin_amdgcn_rcpf(p00 * mrg[2] + p01 * mrg[10]);
    const float inv1 = __builtin_amdgcn_rcpf(p10 * mrg[3] + p11 * mrg[11]);

    const int o = row0 * F + lane;
    if (w == 0) {
        float o00 = (p00 * mrg[4] + p01 * mrg[12]) * inv0 * wf;
        float o01 = (p10 * mrg[5] + p11 * mrg[13]) * inv1 * wf;
        o00 = (o00 > 0.f) ? o00 : (__builtin_amdgcn_exp2f(o00 * LOG2E) - 1.f);
        o01 = (o01 > 0.f) ? o01 : (__builtin_amdgcn_exp2f(o01 * LOG2E) - 1.f);
        out[o] = o00;
        out[o + F] = o01;
    } else {
        float o10 = (p00 * mrg[6] + p01 * mrg[14]) * inv0 * wvf;
        float o11 = (p10 * mrg[7] + p11 * mrg[15]) * inv1 * wvf;
        o10 = (o10 > 0.f) ? o10 : (__builtin_amdgcn_exp2f(o10 * LOG2E) - 1.f);
        o11 = (o11 > 0.f) ? o11 : (__builtin_amdgcn_exp2f(o11 * LOG2E) - 1.f);
        out[262144 + o] = o10;      // 8*N*F
        out[262144 + o + F] = o11;
    }
}

extern "C" void kernel_launch(void* const* d_in, const int* in_sizes, int n_in,
                              void* d_out, int out_size, void* d_ws, size_t ws_size,
                              hipStream_t stream) {
    static const int exp_sizes[11] = {4096, 262144, 32768, 4096, 64, 128, 64, 128, 32, 32, 64};
    bool ok = (n_in == 11) && (out_size == 524288);
    if (ok) {
        for (int k = 0; k < 11; k++) if (in_sizes[k] != exp_sizes[k]) ok = false;
    }
    if (!ok) {
        sentinel_kernel<<<4096, 64, 0, stream>>>((float*)d_out);
        return;
    }

    gat_fused_f32<<<2048, 128, 0, stream>>>(
        (const float*)d_in[0], (const int*)d_in[1],
        (const float*)d_in[2], (const float*)d_in[3],
        (const float*)d_in[4], (const float*)d_in[5],
        (const float*)d_in[6], (const float*)d_in[7],
        (const float*)d_in[8], (const float*)d_in[9],
        (const float*)d_in[10],
        (float*)d_out);
}